// Round 1
// baseline (360.056 us; speedup 1.0000x reference)
//
#include <hip/hip_runtime.h>

// Problem: N=8192 fp32 matrix M, fp32 vector s.
// result = 0.25*sum(M) - 0.5*[ sum_{i<j} M_ij s_i s_j + sum_i M_ii s_i ]
// Memory-bound single-pass reduction: 256 MiB read -> ~42 us floor at 6.3 TB/s.

static constexpr int N_DIM       = 8192;
static constexpr int VEC_PER_ROW = N_DIM / 4;           // 2048 float4 per row
static constexpr int TOTAL_VEC   = N_DIM * VEC_PER_ROW; // 16,777,216
static constexpr int BLOCK       = 256;
static constexpr int GRID        = 8192;                // 32 blocks/CU, 8 float4/thread

__global__ __launch_bounds__(BLOCK) void ising_partial_kernel(
    const float4* __restrict__ mtx4,
    const float*  __restrict__ state,
    float*        __restrict__ partial)
{
    const int tid    = blockIdx.x * BLOCK + threadIdx.x;
    const int stride = GRID * BLOCK;
    const float4* state4 = (const float4*)state;

    float acc = 0.0f;
    for (int v = tid; v < TOTAL_VEC; v += stride) {
        const int row = v >> 11;        // v / 2048 — wave-uniform (64 | 2048)
        const int t   = v & 2047;
        const int j0  = t << 2;

        const float4 m  = mtx4[v];      // coalesced 16B/lane
        const float4 sj = state4[t];    // L1/L2-resident
        const float  si = state[row];   // scalar (wave-uniform)

        // 0.25 * sum(M) term for all 4 elements
        acc += 0.25f * ((m.x + m.y) + (m.z + m.w));

        // per-lane class: j>i -> sj*m ; j==i -> m ; j<i -> 0   (then * -0.5*si)
        float c;
        c  = (j0 + 0 > row) ? (sj.x * m.x) : ((j0 + 0 == row) ? m.x : 0.0f);
        c += (j0 + 1 > row) ? (sj.y * m.y) : ((j0 + 1 == row) ? m.y : 0.0f);
        c += (j0 + 2 > row) ? (sj.z * m.z) : ((j0 + 2 == row) ? m.z : 0.0f);
        c += (j0 + 3 > row) ? (sj.w * m.w) : ((j0 + 3 == row) ? m.w : 0.0f);
        acc -= 0.5f * si * c;
    }

    // wave-64 shuffle reduction
    for (int off = 32; off > 0; off >>= 1)
        acc += __shfl_down(acc, off, 64);

    __shared__ float lds[BLOCK / 64];
    const int lane = threadIdx.x & 63;
    const int wave = threadIdx.x >> 6;
    if (lane == 0) lds[wave] = acc;
    __syncthreads();
    if (threadIdx.x == 0)
        partial[blockIdx.x] = (lds[0] + lds[1]) + (lds[2] + lds[3]);
}

__global__ __launch_bounds__(BLOCK) void ising_final_kernel(
    const float* __restrict__ partial,
    float*       __restrict__ out)
{
    float acc = 0.0f;
    for (int i = threadIdx.x; i < GRID; i += BLOCK)
        acc += partial[i];

    for (int off = 32; off > 0; off >>= 1)
        acc += __shfl_down(acc, off, 64);

    __shared__ float lds[BLOCK / 64];
    const int lane = threadIdx.x & 63;
    const int wave = threadIdx.x >> 6;
    if (lane == 0) lds[wave] = acc;
    __syncthreads();
    if (threadIdx.x == 0)
        out[0] = (lds[0] + lds[1]) + (lds[2] + lds[3]);
}

extern "C" void kernel_launch(void* const* d_in, const int* in_sizes, int n_in,
                              void* d_out, int out_size, void* d_ws, size_t ws_size,
                              hipStream_t stream) {
    const float* mtx   = (const float*)d_in[0];   // [8192*8192] fp32
    const float* state = (const float*)d_in[1];   // [8192] fp32
    float* out     = (float*)d_out;               // scalar fp32
    float* partial = (float*)d_ws;                // GRID floats (32 KB), fully overwritten

    ising_partial_kernel<<<GRID, BLOCK, 0, stream>>>((const float4*)mtx, state, partial);
    ising_final_kernel<<<1, BLOCK, 0, stream>>>(partial, out);
}

// Round 2
// 351.370 us; speedup vs baseline: 1.0247x; 1.0247x over previous
//
#include <hip/hip_runtime.h>

// result = 0.25*sum(M) - 0.5*[ sum_{i<j} M_ij s_i s_j + sum_i M_ii s_i ]
// Row-per-block: row/diagonal are block-scalar -> triangle test is wave-uniform.
// Per-thread: 8 independent float4 loads hoisted (MLP), then ~1.5 VALU/elt.
// Memory-bound: 256 MiB read -> ~40 us at 6.6 TB/s measured ceiling.

static constexpr int N_DIM = 8192;
static constexpr int VPR   = N_DIM / 4;    // 2048 float4 per row
static constexpr int BLOCK = 256;
static constexpr int ITERS = VPR / BLOCK;  // 8 float4 per thread
static constexpr int FBLOCK = 1024;        // final-reduce block

__global__ __launch_bounds__(BLOCK) void ising_row_kernel(
    const float4* __restrict__ mtx4,
    const float*  __restrict__ state,
    float*        __restrict__ partial)
{
    const int   row = blockIdx.x;
    const int   d   = row >> 2;            // diagonal's vec4 index (block-scalar)
    const float p   = -0.5f * state[row];  // one scalar load per block
    const float4* __restrict__ rowp = mtx4 + (size_t)row * VPR;
    const float4* __restrict__ s4   = (const float4*)state;

    // hoist all 8 row loads -> 8 outstanding global_load_dwordx4 per thread
    float4 m[ITERS];
#pragma unroll
    for (int k = 0; k < ITERS; ++k)
        m[k] = rowp[threadIdx.x + (k << 8)];

    float accA = 0.0f;   // sum of all m  (0.25 * sum(M) term)
    float accQ = 0.0f;   // sum over j>i of m*sj, plus m_diag  (scaled by p)
#pragma unroll
    for (int k = 0; k < ITERS; ++k) {
        const int    v  = threadIdx.x + (k << 8);
        const float4 mm = m[k];
        accA += (mm.x + mm.y) + (mm.z + mm.w);
        if (v > d) {                        // wave-uniform except 1 wave/block
            const float4 sj = s4[v];        // L1/L2-resident (32 KiB total)
            accQ = fmaf(mm.x, sj.x, accQ);
            accQ = fmaf(mm.y, sj.y, accQ);
            accQ = fmaf(mm.z, sj.z, accQ);
            accQ = fmaf(mm.w, sj.w, accQ);
        } else if (v == d) {                // exactly one thread per block
            const float4 sj = s4[v];
            const int j0 = v << 2;
            float w;
            w = (j0 + 0 > row) ? sj.x : ((j0 + 0 == row) ? 1.0f : 0.0f);
            accQ = fmaf(mm.x, w, accQ);
            w = (j0 + 1 > row) ? sj.y : ((j0 + 1 == row) ? 1.0f : 0.0f);
            accQ = fmaf(mm.y, w, accQ);
            w = (j0 + 2 > row) ? sj.z : ((j0 + 2 == row) ? 1.0f : 0.0f);
            accQ = fmaf(mm.z, w, accQ);
            w = (j0 + 3 > row) ? sj.w : ((j0 + 3 == row) ? 1.0f : 0.0f);
            accQ = fmaf(mm.w, w, accQ);
        }
    }

    float acc = fmaf(0.25f, accA, p * accQ);

    // wave-64 shuffle reduction, then 4-entry LDS combine
    for (int off = 32; off > 0; off >>= 1)
        acc += __shfl_down(acc, off, 64);

    __shared__ float lds[BLOCK / 64];
    const int lane = threadIdx.x & 63;
    const int wave = threadIdx.x >> 6;
    if (lane == 0) lds[wave] = acc;
    __syncthreads();
    if (threadIdx.x == 0)
        partial[blockIdx.x] = (lds[0] + lds[1]) + (lds[2] + lds[3]);
}

__global__ __launch_bounds__(FBLOCK) void ising_final_kernel(
    const float* __restrict__ partial,
    float*       __restrict__ out)
{
    float acc = 0.0f;
#pragma unroll
    for (int k = 0; k < N_DIM / FBLOCK; ++k)      // 8 each
        acc += partial[threadIdx.x + k * FBLOCK];

    for (int off = 32; off > 0; off >>= 1)
        acc += __shfl_down(acc, off, 64);

    __shared__ float lds[FBLOCK / 64];
    const int lane = threadIdx.x & 63;
    const int wave = threadIdx.x >> 6;
    if (lane == 0) lds[wave] = acc;
    __syncthreads();
    if (threadIdx.x == 0) {
        float s = 0.0f;
#pragma unroll
        for (int w = 0; w < FBLOCK / 64; ++w) s += lds[w];
        out[0] = s;
    }
}

extern "C" void kernel_launch(void* const* d_in, const int* in_sizes, int n_in,
                              void* d_out, int out_size, void* d_ws, size_t ws_size,
                              hipStream_t stream) {
    const float* mtx   = (const float*)d_in[0];   // [8192*8192] fp32
    const float* state = (const float*)d_in[1];   // [8192] fp32
    float* out     = (float*)d_out;
    float* partial = (float*)d_ws;                // 8192 floats, fully overwritten

    ising_row_kernel<<<N_DIM, BLOCK, 0, stream>>>((const float4*)mtx, state, partial);
    ising_final_kernel<<<1, FBLOCK, 0, stream>>>(partial, out);
}

// Round 3
// 349.043 us; speedup vs baseline: 1.0316x; 1.0067x over previous
//
#include <hip/hip_runtime.h>

// result = 0.25*sum(M) - 0.5*[ sum_{i<j} M_ij s_i s_j + sum_i M_ii s_i ]
// Row-per-block. R3 change: hoist ALL 16 loads (8 mtx float4 + 8 state float4)
// before any control flow -> 16 outstanding global_load_dwordx4 per thread,
// then pure ALU with wave-uniform branches. Two accQ accumulators to shorten
// the dependent-FMA chain. Memory-bound target: 256 MiB / 6.6 TB/s ~= 40 us.

static constexpr int N_DIM = 8192;
static constexpr int VPR   = N_DIM / 4;    // 2048 float4 per row
static constexpr int BLOCK = 256;
static constexpr int ITERS = VPR / BLOCK;  // 8 float4 per thread
static constexpr int FBLOCK = 1024;

__global__ __launch_bounds__(BLOCK) void ising_row_kernel(
    const float4* __restrict__ mtx4,
    const float*  __restrict__ state,
    float*        __restrict__ partial)
{
    const int   row = blockIdx.x;
    const int   d   = row >> 2;            // diagonal's vec4 index (block-scalar)
    const float p   = -0.5f * state[row];
    const float4* __restrict__ rowp = mtx4 + (size_t)row * VPR;
    const float4* __restrict__ s4   = (const float4*)state;

    // Hoist all loads before any branch: 16 independent dwordx4 in flight.
    float4 m[ITERS];
    float4 s[ITERS];
#pragma unroll
    for (int k = 0; k < ITERS; ++k)
        m[k] = rowp[threadIdx.x + (k << 8)];   // HBM stream, coalesced 1 KB/wave-instr
#pragma unroll
    for (int k = 0; k < ITERS; ++k)
        s[k] = s4[threadIdx.x + (k << 8)];     // 32 KiB total, L1/L2-resident

    float accA  = 0.0f;                    // sum of all m (0.25*sum(M) term)
    float accQ0 = 0.0f, accQ1 = 0.0f;      // masked dot (scaled by p at the end)
#pragma unroll
    for (int k = 0; k < ITERS; ++k) {
        const int    v  = threadIdx.x + (k << 8);
        const float4 mm = m[k];
        const float4 sj = s[k];
        accA += (mm.x + mm.y) + (mm.z + mm.w);
        if (v > d) {                       // wave-uniform except 1 wave/block
            accQ0 = fmaf(mm.x, sj.x, accQ0);
            accQ1 = fmaf(mm.y, sj.y, accQ1);
            accQ0 = fmaf(mm.z, sj.z, accQ0);
            accQ1 = fmaf(mm.w, sj.w, accQ1);
        } else if (v == d) {               // exactly one thread per block
            const int j0 = v << 2;
            float w;
            w = (j0 + 0 > row) ? sj.x : ((j0 + 0 == row) ? 1.0f : 0.0f);
            accQ0 = fmaf(mm.x, w, accQ0);
            w = (j0 + 1 > row) ? sj.y : ((j0 + 1 == row) ? 1.0f : 0.0f);
            accQ1 = fmaf(mm.y, w, accQ1);
            w = (j0 + 2 > row) ? sj.z : ((j0 + 2 == row) ? 1.0f : 0.0f);
            accQ0 = fmaf(mm.z, w, accQ0);
            w = (j0 + 3 > row) ? sj.w : ((j0 + 3 == row) ? 1.0f : 0.0f);
            accQ1 = fmaf(mm.w, w, accQ1);
        }
    }

    float acc = fmaf(0.25f, accA, p * (accQ0 + accQ1));

    // wave-64 shuffle reduction, then 4-entry LDS combine
    for (int off = 32; off > 0; off >>= 1)
        acc += __shfl_down(acc, off, 64);

    __shared__ float lds[BLOCK / 64];
    const int lane = threadIdx.x & 63;
    const int wave = threadIdx.x >> 6;
    if (lane == 0) lds[wave] = acc;
    __syncthreads();
    if (threadIdx.x == 0)
        partial[blockIdx.x] = (lds[0] + lds[1]) + (lds[2] + lds[3]);
}

__global__ __launch_bounds__(FBLOCK) void ising_final_kernel(
    const float* __restrict__ partial,
    float*       __restrict__ out)
{
    float acc = 0.0f;
#pragma unroll
    for (int k = 0; k < N_DIM / FBLOCK; ++k)
        acc += partial[threadIdx.x + k * FBLOCK];

    for (int off = 32; off > 0; off >>= 1)
        acc += __shfl_down(acc, off, 64);

    __shared__ float lds[FBLOCK / 64];
    const int lane = threadIdx.x & 63;
    const int wave = threadIdx.x >> 6;
    if (lane == 0) lds[wave] = acc;
    __syncthreads();
    if (threadIdx.x == 0) {
        float sum = 0.0f;
#pragma unroll
        for (int w = 0; w < FBLOCK / 64; ++w) sum += lds[w];
        out[0] = sum;
    }
}

extern "C" void kernel_launch(void* const* d_in, const int* in_sizes, int n_in,
                              void* d_out, int out_size, void* d_ws, size_t ws_size,
                              hipStream_t stream) {
    const float* mtx   = (const float*)d_in[0];   // [8192*8192] fp32
    const float* state = (const float*)d_in[1];   // [8192] fp32
    float* out     = (float*)d_out;
    float* partial = (float*)d_ws;                // 8192 floats, fully overwritten

    ising_row_kernel<<<N_DIM, BLOCK, 0, stream>>>((const float4*)mtx, state, partial);
    ising_final_kernel<<<1, FBLOCK, 0, stream>>>(partial, out);
}